// Round 15
// baseline (471.260 us; speedup 1.0000x reference)
//
#include <hip/hip_runtime.h>
#include <hip/hip_bf16.h>

#define NNODES 20000
#define NEDGES 320000
#define NGRAPH 1000

typedef __hip_bfloat16 bf16;
typedef unsigned short u16;
typedef short short8 __attribute__((ext_vector_type(8)));
typedef float f32x4 __attribute__((ext_vector_type(4)));

__device__ __forceinline__ float b2f(bf16 x) { return __bfloat162float(x); }
__device__ __forceinline__ float bu2f(u16 u) { return __uint_as_float(((unsigned)u) << 16); }
__device__ __forceinline__ float lou(unsigned u) { return __uint_as_float(u << 16); }
__device__ __forceinline__ float hiu(unsigned u) { return __uint_as_float(u & 0xffff0000u); }
__device__ __forceinline__ u16 f2bu(float v) {
    __hip_bfloat16 b = __float2bfloat16(v);  // RNE
    return *reinterpret_cast<u16*>(&b);
}

// width-agnostic index fetch (int32 or int64 storage)
__device__ __forceinline__ int idx_at(const void* p, int i, int is64) {
    return is64 ? (int)((const long long*)p)[i] : ((const int*)p)[i];
}

// raw float input fetch (bf16 or fp32 storage)
__device__ __forceinline__ float raw_at(const void* p, size_t i, bool isbf) {
    return isbf ? b2f(((const bf16*)p)[i]) : ((const float*)p)[i];
}

static inline char* align16(char* p) {
    return (char*)(((uintptr_t)p + 15) & ~(uintptr_t)15);
}

// ---------------------------------------------------------------------------
// sniff input encodings (flags[0]: floats bf16?, flags[1]: ei int64?, flags[2]: batch int64?)
// ---------------------------------------------------------------------------
__global__ void sniff_all(const void* __restrict__ x, const void* __restrict__ ei,
                          const void* __restrict__ batch, int* __restrict__ flags) {
    __shared__ int sb[4];
    if (threadIdx.x < 4) sb[threadIdx.x] = 0;
    __syncthreads();
    int gb = 0, gf = 0, ze = 0, zb = 0;
    for (int i = threadIdx.x; i < 8192; i += blockDim.x) {
        float vb = b2f(((const bf16*)x)[i]);
        float vf = ((const float*)x)[i];
        if (fabsf(vb) < 1e4f) gb++;
        if (fabsf(vf) < 1e4f) gf++;
        if (((const int*)ei)[2 * i + 1] == 0) ze++;
        if (((const int*)batch)[2 * i + 1] == 0) zb++;
    }
    atomicAdd(&sb[0], gb); atomicAdd(&sb[1], gf);
    atomicAdd(&sb[2], ze); atomicAdd(&sb[3], zb);
    __syncthreads();
    if (threadIdx.x == 0) {
        flags[0] = (sb[0] >= sb[1]) ? 1 : 0;
        flags[1] = (sb[2] > 6000) ? 1 : 0;
        flags[2] = (sb[3] > 6000) ? 1 : 0;
    }
}

// ---------------------------------------------------------------------------
// fused preprocessing: convert-to-fp32 | ea->bf16 | 4x W fragment-pack |
// DEG zero | POOL/CNT zero. All source reads go to RAW inputs (no intra-
// kernel dependencies). One dispatch instead of seven.
// ---------------------------------------------------------------------------
struct Segs {
    const void* src[29];
    int off[30];
};

__device__ __forceinline__ void wtp_store(u16* __restrict__ dst, const void* __restrict__ src,
                                          int K, int N, int i, bool isbf) {
    int j = i & 7;
    int lane = (i >> 3) & 63;
    int rest = i >> 9;
    int KB = K >> 5;
    int tile = rest / KB, kbi = rest - tile * KB;
    int l16 = lane & 15, quad = lane >> 4;
    int n = tile * 16 + l16;
    int kk = kbi * 32 + quad * 8 + j;
    dst[i] = f2bu(raw_at(src, (size_t)kk * N + n, isbf));
}

__global__ void preprocess(Segs S, const int* __restrict__ flags,
                           float* __restrict__ conv, int total,
                           u16* __restrict__ eah,
                           u16* __restrict__ wt2l, u16* __restrict__ wt2r,
                           u16* __restrict__ wt3l, u16* __restrict__ wt3r,
                           int* __restrict__ deg, float* __restrict__ poolcnt) {
    int i = blockIdx.x * blockDim.x + threadIdx.x;
    bool isbf = flags[0] != 0;
    if (i < total) {
        int lo = 0, hi = 29;
        while (hi - lo > 1) {
            int mid = (lo + hi) >> 1;
            if (i >= S.off[mid]) lo = mid; else hi = mid;
        }
        conv[i] = raw_at(S.src[lo], i - S.off[lo], isbf);
        return;
    }
    i -= total;
    if (i < NEDGES * 4) {                       // edge_attr -> bf16 (raw read)
        eah[i] = isbf ? ((const u16*)S.src[1])[i] : f2bu(((const float*)S.src[1])[i]);
        return;
    }
    i -= NEDGES * 4;
    if (i < 65536) { wtp_store(wt2l, S.src[9],  256, 256, i, isbf); return; }
    i -= 65536;
    if (i < 65536) { wtp_store(wt2r, S.src[11], 256, 256, i, isbf); return; }
    i -= 65536;
    if (i < 16384) { wtp_store(wt3l, S.src[16], 256, 64, i, isbf); return; }
    i -= 16384;
    if (i < 16384) { wtp_store(wt3r, S.src[18], 256, 64, i, isbf); return; }
    i -= 16384;
    if (i < NNODES) { deg[i] = 0; return; }
    i -= NNODES;
    if (i < NGRAPH * 65) poolcnt[i] = 0.f;
}

// ---------------------------------------------------------------------------
// CSR build: histogram -> shfl-scan -> scatter (dst-sorted edge list)
// ---------------------------------------------------------------------------
__global__ void csr_hist(const void* __restrict__ ei, const int* __restrict__ flags,
                         int* __restrict__ deg) {
    int e = blockIdx.x * blockDim.x + threadIdx.x;
    if (e >= NEDGES) return;
    atomicAdd(&deg[idx_at(ei, NEDGES + e, flags[1])], 1);
}

__global__ void csr_scan(const int* __restrict__ deg, int* __restrict__ rowptr,
                         int* __restrict__ cursor) {
    __shared__ int wsum[16];
    __shared__ int wpre[16];
    const int t = threadIdx.x;
    const int wid = t >> 6, lane = t & 63;
    const int base = t * 20;
    int loc[20];
    int s = 0;
#pragma unroll
    for (int j = 0; j < 20; j++) {
        int i = base + j;
        int v = (i < NNODES) ? deg[i] : 0;
        loc[j] = s;
        s += v;
    }
    int incl = s;
#pragma unroll
    for (int o = 1; o < 64; o <<= 1) {
        int n = __shfl_up(incl, o);
        if (lane >= o) incl += n;
    }
    if (lane == 63) wsum[wid] = incl;
    __syncthreads();
    if (wid == 0 && lane < 16) {
        int v = wsum[lane];
        int inc2 = v;
#pragma unroll
        for (int o = 1; o < 16; o <<= 1) {
            int n = __shfl_up(inc2, o);
            if (lane >= o) inc2 += n;
        }
        wpre[lane] = inc2 - v;
    }
    __syncthreads();
    int excl = wpre[wid] + incl - s;
#pragma unroll
    for (int j = 0; j < 20; j++) {
        int i = base + j;
        if (i < NNODES) { rowptr[i] = excl + loc[j]; cursor[i] = excl + loc[j]; }
    }
    if (t == 1023) rowptr[NNODES] = excl + s;
}

__global__ void csr_scatter(const void* __restrict__ ei, const int* __restrict__ flags,
                            int* __restrict__ cursor, int2* __restrict__ csr) {
    int e = blockIdx.x * blockDim.x + threadIdx.x;
    if (e >= NEDGES) return;
    const int i64 = flags[1];
    int src = idx_at(ei, e, i64), dst = idx_at(ei, NEDGES + e, i64);
    int pos = atomicAdd(&cursor[dst], 1);
    csr[pos] = make_int2(src, e);
}

// ---------------------------------------------------------------------------
// VALU GEMM (layer 1, CIN=12): XL = X@Wl+bl (bf16), XR = X@Wr+br (fp32)
// ---------------------------------------------------------------------------
template <int TM, int CIN, int DOUT, bool GUARD>
__global__ __launch_bounds__(256, 2) void lin_gemm(
        const float* __restrict__ X,
        const float* __restrict__ Wl, const float* __restrict__ bl,
        const float* __restrict__ Wr, const float* __restrict__ br,
        u16* __restrict__ XL, float* __restrict__ XR) {
    constexpr int CPT = DOUT / 4;
    constexpr int RG = 256 / CPT;
    constexpr int M = RG * TM;
    __shared__ float xs[M * CIN];

    const int t = threadIdx.x;
    const int ct = t % CPT;
    const int rg = t / CPT;
    const int c0 = ct * 4;
    const int r0 = blockIdx.x * M;

    constexpr int C4 = CIN / 4;
    for (int i = t; i < M * C4; i += 256) {
        int r = i / C4, j = i - r * C4;
        float4 v = make_float4(0.f, 0.f, 0.f, 0.f);
        if (!GUARD || (r0 + r) < NNODES)
            v = *(const float4*)&X[(size_t)(r0 + r) * CIN + j * 4];
        *(float4*)&xs[r * CIN + j * 4] = v;
    }
    __syncthreads();

    float4 accL[TM], accR[TM];
#pragma unroll
    for (int m = 0; m < TM; m++) {
        accL[m] = make_float4(0.f, 0.f, 0.f, 0.f);
        accR[m] = make_float4(0.f, 0.f, 0.f, 0.f);
    }
    const float* xbase = &xs[rg * TM * CIN];
#pragma unroll 4
    for (int k = 0; k < CIN; k++) {
        const float4 wl = *(const float4*)&Wl[k * DOUT + c0];
        const float4 wr = *(const float4*)&Wr[k * DOUT + c0];
#pragma unroll
        for (int m = 0; m < TM; m++) {
            float xv = xbase[m * CIN + k];
            accL[m].x = fmaf(xv, wl.x, accL[m].x);
            accL[m].y = fmaf(xv, wl.y, accL[m].y);
            accL[m].z = fmaf(xv, wl.z, accL[m].z);
            accL[m].w = fmaf(xv, wl.w, accL[m].w);
            accR[m].x = fmaf(xv, wr.x, accR[m].x);
            accR[m].y = fmaf(xv, wr.y, accR[m].y);
            accR[m].z = fmaf(xv, wr.z, accR[m].z);
            accR[m].w = fmaf(xv, wr.w, accR[m].w);
        }
    }

    const float4 b4l = *(const float4*)&bl[c0];
    const float4 b4r = *(const float4*)&br[c0];
#pragma unroll
    for (int m = 0; m < TM; m++) {
        int row = r0 + rg * TM + m;
        if (GUARD && row >= NNODES) continue;
        float l0 = accL[m].x + b4l.x, l1 = accL[m].y + b4l.y;
        float l2 = accL[m].z + b4l.z, l3 = accL[m].w + b4l.w;
        uint2 pk;
        pk.x = (unsigned)f2bu(l0) | ((unsigned)f2bu(l1) << 16);
        pk.y = (unsigned)f2bu(l2) | ((unsigned)f2bu(l3) << 16);
        *(uint2*)&XL[(size_t)row * DOUT + c0] = pk;
        float4 r4;
        r4.x = accR[m].x + b4r.x; r4.y = accR[m].y + b4r.y;
        r4.z = accR[m].z + b4r.z; r4.w = accR[m].w + b4r.w;
        *(float4*)&XR[(size_t)row * DOUT + c0] = r4;
    }
}

// ---------------------------------------------------------------------------
// MFMA GEMM (layers 2/3): XL = X@Wl+bl (bf16 out), XR = X@Wr+br (fp32 out).
// ---------------------------------------------------------------------------
template <int N>
__global__ __launch_bounds__(256) void lin_gemm_mfma(
        const float* __restrict__ X,
        const u16* __restrict__ WlP, const float* __restrict__ bl,
        const u16* __restrict__ WrP, const float* __restrict__ br,
        u16* __restrict__ XL, float* __restrict__ XR) {
    constexpr int K = 256;
    constexpr int KB = K / 32;
    constexpr int NTW = N / 64;
    constexpr int XSTR = 264;
    __shared__ u16 xhi[16 * XSTR];
    __shared__ u16 xlo[16 * XSTR];

    const int t = threadIdx.x;
    const int w = t >> 6, lane = t & 63;
    const int quad = lane >> 4, l16 = lane & 15;
    const int m0 = blockIdx.x * 16;
    const int nbase = w * (N / 4);

    for (int idx = t; idx < 16 * 64; idx += 256) {
        int r = idx >> 6, c4 = idx & 63;
        float4 v = *(const float4*)&X[(size_t)(m0 + r) * K + c4 * 4];
        float f[4] = {v.x, v.y, v.z, v.w};
        ushort4 hi, lo;
        u16 h;
        h = f2bu(f[0]); hi.x = h; lo.x = f2bu(f[0] - bu2f(h));
        h = f2bu(f[1]); hi.y = h; lo.y = f2bu(f[1] - bu2f(h));
        h = f2bu(f[2]); hi.z = h; lo.z = f2bu(f[2] - bu2f(h));
        h = f2bu(f[3]); hi.w = h; lo.w = f2bu(f[3] - bu2f(h));
        *(ushort4*)&xhi[r * XSTR + c4 * 4] = hi;
        *(ushort4*)&xlo[r * XSTR + c4 * 4] = lo;
    }
    __syncthreads();

    f32x4 accL[NTW], accR[NTW];
#pragma unroll
    for (int i = 0; i < NTW; i++) {
        accL[i] = (f32x4){0.f, 0.f, 0.f, 0.f};
        accR[i] = (f32x4){0.f, 0.f, 0.f, 0.f};
    }

    const int abase = l16 * XSTR + quad * 8;
#pragma unroll
    for (int kbi = 0; kbi < KB; kbi++) {
        short8 ahi = *(const short8*)&xhi[abase + kbi * 32];
        short8 alo = *(const short8*)&xlo[abase + kbi * 32];
#pragma unroll
        for (int i = 0; i < NTW; i++) {
            int tg = (nbase >> 4) + i;
            size_t off = ((size_t)(tg * KB + kbi) * 64 + lane) * 8;
            short8 bL = *(const short8*)&WlP[off];
            short8 bR = *(const short8*)&WrP[off];
            accL[i] = __builtin_amdgcn_mfma_f32_16x16x32_bf16(ahi, bL, accL[i], 0, 0, 0);
            accL[i] = __builtin_amdgcn_mfma_f32_16x16x32_bf16(alo, bL, accL[i], 0, 0, 0);
            accR[i] = __builtin_amdgcn_mfma_f32_16x16x32_bf16(ahi, bR, accR[i], 0, 0, 0);
            accR[i] = __builtin_amdgcn_mfma_f32_16x16x32_bf16(alo, bR, accR[i], 0, 0, 0);
        }
    }

#pragma unroll
    for (int i = 0; i < NTW; i++) {
        int col = nbase + i * 16 + l16;
        float bLv = bl[col], bRv = br[col];
#pragma unroll
        for (int r = 0; r < 4; r++) {
            int row = m0 + quad * 4 + r;
            XL[(size_t)row * N + col] = f2bu(accL[i][r] + bLv);
            XR[(size_t)row * N + col] = accR[i][r] + bRv;
        }
    }
}

// ---------------------------------------------------------------------------
// Fused GATv2 edge pipeline, one block per dst, one wave per head.
// Wave split into 8 groups x 8 lanes; each group owns one edge per iter,
// each lane owns 8 channels (16B bf16 load). Per-edge share of group-uniform
// work (ea decode, addressing, shfl tree 3 steps) halves vs 16-lane groups.
// POOLF: fuse global mean-pool atomics into the epilogue (layer 3).
// ---------------------------------------------------------------------------
template <int H, bool ELU, bool POOLF>
__global__ __launch_bounds__(H * 64, 4) void gat_agg(
                        const int* __restrict__ rowptr, const int2* __restrict__ csr,
                        const u16* __restrict__ XL, const float* __restrict__ XR,
                        const u16* __restrict__ eah,  // [E][4] bf16
                        const float* __restrict__ We, const float* __restrict__ att,
                        const float* __restrict__ bias, float* __restrict__ out,
                        const void* __restrict__ batch, const int* __restrict__ flags,
                        float* __restrict__ pool, float* __restrict__ cnt) {
    const int Dout = H * 64;
    const int dst = blockIdx.x;
    const int t = threadIdx.x;
    const int h = t >> 6;            // wave == head
    const int lane = t & 63;
    const int g = lane >> 3;         // edge-group 0..7
    const int k = lane & 7;          // channel-slot
    const int c0 = h * 64 + k * 8;   // first of this lane's 8 channels

    float W[4][8], AT[8], XRv[8];
#pragma unroll
    for (int kk = 0; kk < 4; kk++) {
        float4 a = *(const float4*)&We[kk * Dout + c0];
        float4 b = *(const float4*)&We[kk * Dout + c0 + 4];
        W[kk][0] = a.x; W[kk][1] = a.y; W[kk][2] = a.z; W[kk][3] = a.w;
        W[kk][4] = b.x; W[kk][5] = b.y; W[kk][6] = b.z; W[kk][7] = b.w;
    }
    {
        float4 a = *(const float4*)&att[c0];
        float4 b = *(const float4*)&att[c0 + 4];
        AT[0] = a.x; AT[1] = a.y; AT[2] = a.z; AT[3] = a.w;
        AT[4] = b.x; AT[5] = b.y; AT[6] = b.z; AT[7] = b.w;
        float4 c = *(const float4*)&XR[dst * Dout + c0];
        float4 d = *(const float4*)&XR[dst * Dout + c0 + 4];
        XRv[0] = c.x; XRv[1] = c.y; XRv[2] = c.z; XRv[3] = c.w;
        XRv[4] = d.x; XRv[5] = d.y; XRv[6] = d.z; XRv[7] = d.w;
    }

    const int i0 = rowptr[dst], i1 = rowptr[dst + 1];
    const int niter = (i1 - i0 + 7) >> 3;

    float l = 0.f;
    float acc[8];
#pragma unroll
    for (int c = 0; c < 8; c++) acc[c] = 0.f;

#define GAT_EDGE_BODY(E_IDX)                                                     \
    {                                                                            \
        int e_ = (E_IDX);                                                        \
        bool valid_ = e_ < i1;                                                   \
        int2 se_ = csr[valid_ ? e_ : i0];                                        \
        uint4 xu_ = *(const uint4*)&XL[se_.x * Dout + c0];                       \
        uint2 au_ = *(const uint2*)&eah[se_.y * 4];                              \
        float xl_[8];                                                            \
        xl_[0] = lou(xu_.x); xl_[1] = hiu(xu_.x);                                \
        xl_[2] = lou(xu_.y); xl_[3] = hiu(xu_.y);                                \
        xl_[4] = lou(xu_.z); xl_[5] = hiu(xu_.z);                                \
        xl_[6] = lou(xu_.w); xl_[7] = hiu(xu_.w);                                \
        float A0_ = lou(au_.x), A1_ = hiu(au_.x);                                \
        float A2_ = lou(au_.y), A3_ = hiu(au_.y);                                \
        float v_ = 0.f;                                                          \
        _Pragma("unroll")                                                        \
        for (int c = 0; c < 8; c++) {                                            \
            float z = fmaf(A0_, W[0][c], fmaf(A1_, W[1][c],                      \
                      fmaf(A2_, W[2][c], fmaf(A3_, W[3][c], xl_[c] + XRv[c])))); \
            z = fmaxf(z, 0.2f * z);                                              \
            v_ = fmaf(z, AT[c], v_);                                             \
        }                                                                        \
        v_ += __shfl_xor(v_, 1);                                                 \
        v_ += __shfl_xor(v_, 2);                                                 \
        v_ += __shfl_xor(v_, 4);                                                 \
        float p_ = valid_ ? __expf(v_) : 0.f;                                    \
        l += p_;                                                                 \
        _Pragma("unroll")                                                        \
        for (int c = 0; c < 8; c++) acc[c] = fmaf(p_, xl_[c], acc[c]);           \
    }

    int it = 0;
    for (; it + 2 <= niter; it += 2) {
        int eb = i0 + g + it * 8;
        GAT_EDGE_BODY(eb)
        GAT_EDGE_BODY(eb + 8)
    }
    if (it < niter) {
        GAT_EDGE_BODY(i0 + g + it * 8)
    }
#undef GAT_EDGE_BODY

    // combine the 8 edge-groups (once per dst)
#pragma unroll
    for (int o = 8; o < 64; o <<= 1) {
        l += __shfl_xor(l, o);
#pragma unroll
        for (int c = 0; c < 8; c++) acc[c] += __shfl_xor(acc[c], o);
    }

    if (g == 0) {
        float inv = 1.f / (l + 1e-16f);
        float o[8];
        float4 ba = *(const float4*)&bias[c0];
        float4 bb = *(const float4*)&bias[c0 + 4];
        float bs[8] = {ba.x, ba.y, ba.z, ba.w, bb.x, bb.y, bb.z, bb.w};
#pragma unroll
        for (int c = 0; c < 8; c++) {
            float v = fmaf(acc[c], inv, bs[c]);
            if (ELU) v = v > 0.f ? v : expf(v) - 1.f;
            o[c] = v;
        }
        if (POOLF) {
            int b = idx_at(batch, dst, flags[2]);
#pragma unroll
            for (int c = 0; c < 8; c++) atomicAdd(&pool[b * 64 + c0 + c], o[c]);
            if (lane == 0) atomicAdd(&cnt[b], 1.f);
        } else {
            *(float4*)&out[dst * Dout + c0] = make_float4(o[0], o[1], o[2], o[3]);
            *(float4*)&out[dst * Dout + c0 + 4] = make_float4(o[4], o[5], o[6], o[7]);
        }
    }
}

// ---------------------------------------------------------------------------
// MLP head: one block (64 threads) per graph; fp32 output
// ---------------------------------------------------------------------------
__global__ void mlp_head(const float* __restrict__ pool, const float* __restrict__ cnt,
                         const float* __restrict__ mW1, const float* __restrict__ mb1,
                         const float* __restrict__ mW2, const float* __restrict__ mb2,
                         const float* __restrict__ mW3, const float* __restrict__ mb3,
                         float* __restrict__ out) {
    __shared__ float g[64], s1[32], s2[16];
    int b = blockIdx.x, t = threadIdx.x;
    float c = fmaxf(cnt[b], 1.f);
    g[t] = pool[b * 64 + t] / c;
    __syncthreads();
    if (t < 32) {
        float a = 0.f;
        for (int k = 0; k < 64; k++) a = fmaf(g[k], mW1[k * 32 + t], a);
        s1[t] = fmaxf(a + mb1[t], 0.f);
    }
    __syncthreads();
    if (t < 16) {
        float a = 0.f;
        for (int k = 0; k < 32; k++) a = fmaf(s1[k], mW2[k * 16 + t], a);
        s2[t] = fmaxf(a + mb2[t], 0.f);
    }
    __syncthreads();
    if (t < 4) {
        float a = 0.f;
        for (int k = 0; k < 16; k++) a = fmaf(s2[k], mW3[k * 4 + t], a);
        out[b * 4 + t] = a + mb3[t];
    }
}

// ---------------------------------------------------------------------------

extern "C" void kernel_launch(void* const* d_in, const int* in_sizes, int n_in,
                              void* d_out, int out_size, void* d_ws, size_t ws_size,
                              hipStream_t stream) {
    const void* ei    = d_in[1];
    const void* batch = d_in[3];

    // ---- canonicalization table: the 29 float inputs in dict order ----
    int fidx[29];
    fidx[0] = 0;  // x
    fidx[1] = 2;  // edge_attr
    for (int i = 0; i < 21; i++) fidx[2 + i] = 4 + i;
    for (int i = 0; i < 6; i++) fidx[23 + i] = 25 + i;

    Segs S;
    int off = 0;
    for (int i = 0; i < 29; i++) {
        S.src[i] = d_in[fidx[i]];
        S.off[i] = off;
        off += in_sizes[fidx[i]];
    }
    S.off[29] = off;
    const int total = off;

    // ---- workspace layout (16B-aligned sections) ----
    char* p = (char*)d_ws;
    int*   FLAGS  = (int*)p;                 p += 16;
    float* CONV   = (float*)p;               p += sizeof(float) * total;  p = align16(p);
    int*   DEG    = (int*)p;                 p += sizeof(int) * NNODES;
    int*   ROWPTR = (int*)p;                 p += sizeof(int) * (NNODES + 1);
    int*   CURSOR = (int*)p;                 p += sizeof(int) * (NNODES + 1);  p = align16(p);
    int2*  CSR    = (int2*)p;                p += sizeof(int2) * NEDGES;  p = align16(p);
    u16*   EAH    = (u16*)p;                 p += sizeof(u16) * NEDGES * 4;  p = align16(p);
    u16*   WT2L   = (u16*)p;                 p += sizeof(u16) * 256 * 256;
    u16*   WT2R   = (u16*)p;                 p += sizeof(u16) * 256 * 256;
    u16*   WT3L   = (u16*)p;                 p += sizeof(u16) * 64 * 256;
    u16*   WT3R   = (u16*)p;                 p += sizeof(u16) * 64 * 256;  p = align16(p);
    u16*   XLb    = (u16*)p;                 p += sizeof(u16) * NNODES * 256;  p = align16(p);
    float* XRb    = (float*)p;               p += sizeof(float) * NNODES * 256;
    float* ACC    = (float*)p;               p += sizeof(float) * NNODES * 256;
    float* POOL   = (float*)p;               p += sizeof(float) * NGRAPH * 64;
    float* CNT    = (float*)p;               p += sizeof(float) * NGRAPH;

    const float* CX  = CONV + S.off[0];
    const float* CP[21];
    for (int i = 0; i < 21; i++) CP[i] = CONV + S.off[2 + i];
    const float* CmW1 = CONV + S.off[23];
    const float* Cmb1 = CONV + S.off[24];
    const float* CmW2 = CONV + S.off[25];
    const float* Cmb2 = CONV + S.off[26];
    const float* CmW3 = CONV + S.off[27];
    const float* Cmb3 = CONV + S.off[28];

    // ---- sniff + fused preprocessing (convert/ea/W-pack/zero-init) ----
    sniff_all<<<1, 256, 0, stream>>>(d_in[0], ei, batch, FLAGS);
    int pre_total = total + NEDGES * 4 + 65536 * 2 + 16384 * 2 + NNODES + NGRAPH * 65;
    preprocess<<<(pre_total + 255) / 256, 256, 0, stream>>>(
        S, FLAGS, CONV, total, EAH, WT2L, WT2R, WT3L, WT3R, DEG, POOL);

    // ---- CSR build (graph identical across layers: build once) ----
    csr_hist<<<(NEDGES + 255) / 256, 256, 0, stream>>>(ei, FLAGS, DEG);
    csr_scan<<<1, 1024, 0, stream>>>(DEG, ROWPTR, CURSOR);
    csr_scatter<<<(NEDGES + 255) / 256, 256, 0, stream>>>(ei, FLAGS, CURSOR, CSR);

    // ---- layer 1: x (N x 12) -> ACC (N x 256), ELU ----
    lin_gemm<4, 12, 256, false><<<NNODES / 16, 256, 0, stream>>>(CX, CP[0], CP[1], CP[2], CP[3], XLb, XRb);
    gat_agg<4, true, false><<<NNODES, 256, 0, stream>>>(ROWPTR, CSR, XLb, XRb, EAH,
        CP[4], CP[5], CP[6], ACC, batch, FLAGS, POOL, CNT);

    // ---- layer 2: ACC (N x 256) -> ACC, ELU (MFMA GEMM) ----
    lin_gemm_mfma<256><<<NNODES / 16, 256, 0, stream>>>(ACC, WT2L, CP[8], WT2R, CP[10], XLb, XRb);
    gat_agg<4, true, false><<<NNODES, 256, 0, stream>>>(ROWPTR, CSR, XLb, XRb, EAH,
        CP[11], CP[12], CP[13], ACC, batch, FLAGS, POOL, CNT);

    // ---- layer 3: ACC (N x 256) -> pooled directly (MFMA GEMM + fused pool) ----
    lin_gemm_mfma<64><<<NNODES / 16, 256, 0, stream>>>(ACC, WT3L, CP[15], WT3R, CP[17], XLb, XRb);
    gat_agg<1, false, true><<<NNODES, 64, 0, stream>>>(ROWPTR, CSR, XLb, XRb, EAH,
        CP[18], CP[19], CP[20], ACC, batch, FLAGS, POOL, CNT);

    // ---- MLP head ----
    mlp_head<<<NGRAPH, 64, 0, stream>>>(POOL, CNT, CmW1, Cmb1, CmW2, Cmb2, CmW3, Cmb3, (float*)d_out);
}

// Round 16
// 405.443 us; speedup vs baseline: 1.1623x; 1.1623x over previous
//
#include <hip/hip_runtime.h>
#include <hip/hip_bf16.h>

#define NNODES 20000
#define NEDGES 320000
#define NGRAPH 1000

typedef __hip_bfloat16 bf16;
typedef unsigned short u16;
typedef short short8 __attribute__((ext_vector_type(8)));
typedef float f32x4 __attribute__((ext_vector_type(4)));

__device__ __forceinline__ float b2f(bf16 x) { return __bfloat162float(x); }
__device__ __forceinline__ float bu2f(u16 u) { return __uint_as_float(((unsigned)u) << 16); }
__device__ __forceinline__ u16 f2bu(float v) {
    __hip_bfloat16 b = __float2bfloat16(v);  // RNE
    return *reinterpret_cast<u16*>(&b);
}

// width-agnostic index fetch (int32 or int64 storage)
__device__ __forceinline__ int idx_at(const void* p, int i, int is64) {
    return is64 ? (int)((const long long*)p)[i] : ((const int*)p)[i];
}

// raw float input fetch (bf16 or fp32 storage)
__device__ __forceinline__ float raw_at(const void* p, size_t i, bool isbf) {
    return isbf ? b2f(((const bf16*)p)[i]) : ((const float*)p)[i];
}

static inline char* align16(char* p) {
    return (char*)(((uintptr_t)p + 15) & ~(uintptr_t)15);
}

// ---------------------------------------------------------------------------
// sniff input encodings (flags[0]: floats bf16?, flags[1]: ei int64?, flags[2]: batch int64?)
// ---------------------------------------------------------------------------
__global__ void sniff_all(const void* __restrict__ x, const void* __restrict__ ei,
                          const void* __restrict__ batch, int* __restrict__ flags) {
    __shared__ int sb[4];
    if (threadIdx.x < 4) sb[threadIdx.x] = 0;
    __syncthreads();
    int gb = 0, gf = 0, ze = 0, zb = 0;
    for (int i = threadIdx.x; i < 8192; i += blockDim.x) {
        float vb = b2f(((const bf16*)x)[i]);
        float vf = ((const float*)x)[i];
        if (fabsf(vb) < 1e4f) gb++;
        if (fabsf(vf) < 1e4f) gf++;
        if (((const int*)ei)[2 * i + 1] == 0) ze++;
        if (((const int*)batch)[2 * i + 1] == 0) zb++;
    }
    atomicAdd(&sb[0], gb); atomicAdd(&sb[1], gf);
    atomicAdd(&sb[2], ze); atomicAdd(&sb[3], zb);
    __syncthreads();
    if (threadIdx.x == 0) {
        flags[0] = (sb[0] >= sb[1]) ? 1 : 0;
        flags[1] = (sb[2] > 6000) ? 1 : 0;
        flags[2] = (sb[3] > 6000) ? 1 : 0;
    }
}

// ---------------------------------------------------------------------------
// fused preprocessing: convert-to-fp32 | ea->bf16 | 4x W fragment-pack |
// DEG zero | POOL/CNT zero. All source reads from RAW inputs.
// ---------------------------------------------------------------------------
struct Segs {
    const void* src[29];
    int off[30];
};

__device__ __forceinline__ void wtp_store(u16* __restrict__ dst, const void* __restrict__ src,
                                          int K, int N, int i, bool isbf) {
    int j = i & 7;
    int lane = (i >> 3) & 63;
    int rest = i >> 9;
    int KB = K >> 5;
    int tile = rest / KB, kbi = rest - tile * KB;
    int l16 = lane & 15, quad = lane >> 4;
    int n = tile * 16 + l16;
    int kk = kbi * 32 + quad * 8 + j;
    dst[i] = f2bu(raw_at(src, (size_t)kk * N + n, isbf));
}

__global__ void preprocess(Segs S, const int* __restrict__ flags,
                           float* __restrict__ conv, int total,
                           u16* __restrict__ eah,
                           u16* __restrict__ wt2l, u16* __restrict__ wt2r,
                           u16* __restrict__ wt3l, u16* __restrict__ wt3r,
                           int* __restrict__ deg, float* __restrict__ poolcnt) {
    int i = blockIdx.x * blockDim.x + threadIdx.x;
    bool isbf = flags[0] != 0;
    if (i < total) {
        int lo = 0, hi = 29;
        while (hi - lo > 1) {
            int mid = (lo + hi) >> 1;
            if (i >= S.off[mid]) lo = mid; else hi = mid;
        }
        conv[i] = raw_at(S.src[lo], i - S.off[lo], isbf);
        return;
    }
    i -= total;
    if (i < NEDGES * 4) {                       // edge_attr -> bf16 (raw read)
        eah[i] = isbf ? ((const u16*)S.src[1])[i] : f2bu(((const float*)S.src[1])[i]);
        return;
    }
    i -= NEDGES * 4;
    if (i < 65536) { wtp_store(wt2l, S.src[9],  256, 256, i, isbf); return; }
    i -= 65536;
    if (i < 65536) { wtp_store(wt2r, S.src[11], 256, 256, i, isbf); return; }
    i -= 65536;
    if (i < 16384) { wtp_store(wt3l, S.src[16], 256, 64, i, isbf); return; }
    i -= 16384;
    if (i < 16384) { wtp_store(wt3r, S.src[18], 256, 64, i, isbf); return; }
    i -= 16384;
    if (i < NNODES) { deg[i] = 0; return; }
    i -= NNODES;
    if (i < NGRAPH * 65) poolcnt[i] = 0.f;
}

// ---------------------------------------------------------------------------
// CSR build: histogram -> shfl-scan -> scatter (dst-sorted edge list)
// ---------------------------------------------------------------------------
__global__ void csr_hist(const void* __restrict__ ei, const int* __restrict__ flags,
                         int* __restrict__ deg) {
    int e = blockIdx.x * blockDim.x + threadIdx.x;
    if (e >= NEDGES) return;
    atomicAdd(&deg[idx_at(ei, NEDGES + e, flags[1])], 1);
}

__global__ void csr_scan(const int* __restrict__ deg, int* __restrict__ rowptr,
                         int* __restrict__ cursor) {
    __shared__ int wsum[16];
    __shared__ int wpre[16];
    const int t = threadIdx.x;
    const int wid = t >> 6, lane = t & 63;
    const int base = t * 20;
    int loc[20];
    int s = 0;
#pragma unroll
    for (int j = 0; j < 20; j++) {
        int i = base + j;
        int v = (i < NNODES) ? deg[i] : 0;
        loc[j] = s;
        s += v;
    }
    int incl = s;
#pragma unroll
    for (int o = 1; o < 64; o <<= 1) {
        int n = __shfl_up(incl, o);
        if (lane >= o) incl += n;
    }
    if (lane == 63) wsum[wid] = incl;
    __syncthreads();
    if (wid == 0 && lane < 16) {
        int v = wsum[lane];
        int inc2 = v;
#pragma unroll
        for (int o = 1; o < 16; o <<= 1) {
            int n = __shfl_up(inc2, o);
            if (lane >= o) inc2 += n;
        }
        wpre[lane] = inc2 - v;
    }
    __syncthreads();
    int excl = wpre[wid] + incl - s;
#pragma unroll
    for (int j = 0; j < 20; j++) {
        int i = base + j;
        if (i < NNODES) { rowptr[i] = excl + loc[j]; cursor[i] = excl + loc[j]; }
    }
    if (t == 1023) rowptr[NNODES] = excl + s;
}

__global__ void csr_scatter(const void* __restrict__ ei, const int* __restrict__ flags,
                            int* __restrict__ cursor, int2* __restrict__ csr) {
    int e = blockIdx.x * blockDim.x + threadIdx.x;
    if (e >= NEDGES) return;
    const int i64 = flags[1];
    int src = idx_at(ei, e, i64), dst = idx_at(ei, NEDGES + e, i64);
    int pos = atomicAdd(&cursor[dst], 1);
    csr[pos] = make_int2(src, e);
}

// ---------------------------------------------------------------------------
// VALU GEMM (layer 1, CIN=12): XL = X@Wl+bl (bf16), XR = X@Wr+br (fp32)
// ---------------------------------------------------------------------------
template <int TM, int CIN, int DOUT, bool GUARD>
__global__ __launch_bounds__(256, 2) void lin_gemm(
        const float* __restrict__ X,
        const float* __restrict__ Wl, const float* __restrict__ bl,
        const float* __restrict__ Wr, const float* __restrict__ br,
        u16* __restrict__ XL, float* __restrict__ XR) {
    constexpr int CPT = DOUT / 4;
    constexpr int RG = 256 / CPT;
    constexpr int M = RG * TM;
    __shared__ float xs[M * CIN];

    const int t = threadIdx.x;
    const int ct = t % CPT;
    const int rg = t / CPT;
    const int c0 = ct * 4;
    const int r0 = blockIdx.x * M;

    constexpr int C4 = CIN / 4;
    for (int i = t; i < M * C4; i += 256) {
        int r = i / C4, j = i - r * C4;
        float4 v = make_float4(0.f, 0.f, 0.f, 0.f);
        if (!GUARD || (r0 + r) < NNODES)
            v = *(const float4*)&X[(size_t)(r0 + r) * CIN + j * 4];
        *(float4*)&xs[r * CIN + j * 4] = v;
    }
    __syncthreads();

    float4 accL[TM], accR[TM];
#pragma unroll
    for (int m = 0; m < TM; m++) {
        accL[m] = make_float4(0.f, 0.f, 0.f, 0.f);
        accR[m] = make_float4(0.f, 0.f, 0.f, 0.f);
    }
    const float* xbase = &xs[rg * TM * CIN];
#pragma unroll 4
    for (int k = 0; k < CIN; k++) {
        const float4 wl = *(const float4*)&Wl[k * DOUT + c0];
        const float4 wr = *(const float4*)&Wr[k * DOUT + c0];
#pragma unroll
        for (int m = 0; m < TM; m++) {
            float xv = xbase[m * CIN + k];
            accL[m].x = fmaf(xv, wl.x, accL[m].x);
            accL[m].y = fmaf(xv, wl.y, accL[m].y);
            accL[m].z = fmaf(xv, wl.z, accL[m].z);
            accL[m].w = fmaf(xv, wl.w, accL[m].w);
            accR[m].x = fmaf(xv, wr.x, accR[m].x);
            accR[m].y = fmaf(xv, wr.y, accR[m].y);
            accR[m].z = fmaf(xv, wr.z, accR[m].z);
            accR[m].w = fmaf(xv, wr.w, accR[m].w);
        }
    }

    const float4 b4l = *(const float4*)&bl[c0];
    const float4 b4r = *(const float4*)&br[c0];
#pragma unroll
    for (int m = 0; m < TM; m++) {
        int row = r0 + rg * TM + m;
        if (GUARD && row >= NNODES) continue;
        float l0 = accL[m].x + b4l.x, l1 = accL[m].y + b4l.y;
        float l2 = accL[m].z + b4l.z, l3 = accL[m].w + b4l.w;
        uint2 pk;
        pk.x = (unsigned)f2bu(l0) | ((unsigned)f2bu(l1) << 16);
        pk.y = (unsigned)f2bu(l2) | ((unsigned)f2bu(l3) << 16);
        *(uint2*)&XL[(size_t)row * DOUT + c0] = pk;
        float4 r4;
        r4.x = accR[m].x + b4r.x; r4.y = accR[m].y + b4r.y;
        r4.z = accR[m].z + b4r.z; r4.w = accR[m].w + b4r.w;
        *(float4*)&XR[(size_t)row * DOUT + c0] = r4;
    }
}

// ---------------------------------------------------------------------------
// MFMA GEMM (layers 2/3): XL = X@Wl+bl (bf16 out), XR = X@Wr+br (fp32 out).
// ---------------------------------------------------------------------------
template <int N>
__global__ __launch_bounds__(256) void lin_gemm_mfma(
        const float* __restrict__ X,
        const u16* __restrict__ WlP, const float* __restrict__ bl,
        const u16* __restrict__ WrP, const float* __restrict__ br,
        u16* __restrict__ XL, float* __restrict__ XR) {
    constexpr int K = 256;
    constexpr int KB = K / 32;
    constexpr int NTW = N / 64;
    constexpr int XSTR = 264;
    __shared__ u16 xhi[16 * XSTR];
    __shared__ u16 xlo[16 * XSTR];

    const int t = threadIdx.x;
    const int w = t >> 6, lane = t & 63;
    const int quad = lane >> 4, l16 = lane & 15;
    const int m0 = blockIdx.x * 16;
    const int nbase = w * (N / 4);

    for (int idx = t; idx < 16 * 64; idx += 256) {
        int r = idx >> 6, c4 = idx & 63;
        float4 v = *(const float4*)&X[(size_t)(m0 + r) * K + c4 * 4];
        float f[4] = {v.x, v.y, v.z, v.w};
        ushort4 hi, lo;
        u16 h;
        h = f2bu(f[0]); hi.x = h; lo.x = f2bu(f[0] - bu2f(h));
        h = f2bu(f[1]); hi.y = h; lo.y = f2bu(f[1] - bu2f(h));
        h = f2bu(f[2]); hi.z = h; lo.z = f2bu(f[2] - bu2f(h));
        h = f2bu(f[3]); hi.w = h; lo.w = f2bu(f[3] - bu2f(h));
        *(ushort4*)&xhi[r * XSTR + c4 * 4] = hi;
        *(ushort4*)&xlo[r * XSTR + c4 * 4] = lo;
    }
    __syncthreads();

    f32x4 accL[NTW], accR[NTW];
#pragma unroll
    for (int i = 0; i < NTW; i++) {
        accL[i] = (f32x4){0.f, 0.f, 0.f, 0.f};
        accR[i] = (f32x4){0.f, 0.f, 0.f, 0.f};
    }

    const int abase = l16 * XSTR + quad * 8;
#pragma unroll
    for (int kbi = 0; kbi < KB; kbi++) {
        short8 ahi = *(const short8*)&xhi[abase + kbi * 32];
        short8 alo = *(const short8*)&xlo[abase + kbi * 32];
#pragma unroll
        for (int i = 0; i < NTW; i++) {
            int tg = (nbase >> 4) + i;
            size_t off = ((size_t)(tg * KB + kbi) * 64 + lane) * 8;
            short8 bL = *(const short8*)&WlP[off];
            short8 bR = *(const short8*)&WrP[off];
            accL[i] = __builtin_amdgcn_mfma_f32_16x16x32_bf16(ahi, bL, accL[i], 0, 0, 0);
            accL[i] = __builtin_amdgcn_mfma_f32_16x16x32_bf16(alo, bL, accL[i], 0, 0, 0);
            accR[i] = __builtin_amdgcn_mfma_f32_16x16x32_bf16(ahi, bR, accR[i], 0, 0, 0);
            accR[i] = __builtin_amdgcn_mfma_f32_16x16x32_bf16(alo, bR, accR[i], 0, 0, 0);
        }
    }

#pragma unroll
    for (int i = 0; i < NTW; i++) {
        int col = nbase + i * 16 + l16;
        float bLv = bl[col], bRv = br[col];
#pragma unroll
        for (int r = 0; r < 4; r++) {
            int row = m0 + quad * 4 + r;
            XL[(size_t)row * N + col] = f2bu(accL[i][r] + bLv);
            XR[(size_t)row * N + col] = accR[i][r] + bRv;
        }
    }
}

// ---------------------------------------------------------------------------
// Fused GATv2 edge pipeline (round-14 verified body: 63.5us @ 81% VALUBusy).
// One block per dst, one wave per head; wave = 4 groups x 16 lanes; group
// owns one edge per iter, lane owns 4 channels (8B bf16 load).
// POOLF: fuse global mean-pool atomics into the epilogue (layer 3).
// ---------------------------------------------------------------------------
template <int H, bool ELU, bool POOLF>
__global__ __launch_bounds__(H * 64, 4) void gat_agg(
                        const int* __restrict__ rowptr, const int2* __restrict__ csr,
                        const u16* __restrict__ XL, const float* __restrict__ XR,
                        const u16* __restrict__ eah,  // [E][4] bf16
                        const float* __restrict__ We, const float* __restrict__ att,
                        const float* __restrict__ bias, float* __restrict__ out,
                        const void* __restrict__ batch, const int* __restrict__ flags,
                        float* __restrict__ pool, float* __restrict__ cnt) {
    const int Dout = H * 64;
    const int dst = blockIdx.x;
    const int t = threadIdx.x;
    const int h = t >> 6;            // wave == head
    const int lane = t & 63;
    const int g = lane >> 4;         // edge-group 0..3
    const int k = lane & 15;         // channel-slot
    const int c0 = h * 64 + k * 4;   // first of this lane's 4 channels

    const float4 w0 = *(const float4*)&We[0 * Dout + c0];
    const float4 w1 = *(const float4*)&We[1 * Dout + c0];
    const float4 w2 = *(const float4*)&We[2 * Dout + c0];
    const float4 w3 = *(const float4*)&We[3 * Dout + c0];
    const float4 at = *(const float4*)&att[c0];
    const float4 xr = *(const float4*)&XR[dst * Dout + c0];

    const int i0 = rowptr[dst], i1 = rowptr[dst + 1];
    const int niter = (i1 - i0 + 3) >> 2;

    float l = 0.f;
    float4 acc = make_float4(0.f, 0.f, 0.f, 0.f);

#define GAT_EDGE_BODY(E_IDX)                                                     \
    {                                                                            \
        int e_ = (E_IDX);                                                        \
        bool valid_ = e_ < i1;                                                   \
        int2 se_ = csr[valid_ ? e_ : i0];                                        \
        uint2 xu_ = *(const uint2*)&XL[se_.x * Dout + c0];                       \
        uint2 au_ = *(const uint2*)&eah[se_.y * 4];                              \
        float xl0_ = __uint_as_float(xu_.x << 16);                               \
        float xl1_ = __uint_as_float(xu_.x & 0xffff0000u);                       \
        float xl2_ = __uint_as_float(xu_.y << 16);                               \
        float xl3_ = __uint_as_float(xu_.y & 0xffff0000u);                       \
        float A0_ = __uint_as_float(au_.x << 16);                                \
        float A1_ = __uint_as_float(au_.x & 0xffff0000u);                        \
        float A2_ = __uint_as_float(au_.y << 16);                                \
        float A3_ = __uint_as_float(au_.y & 0xffff0000u);                        \
        float z0_ = fmaf(A0_, w0.x, fmaf(A1_, w1.x, fmaf(A2_, w2.x, fmaf(A3_, w3.x, xl0_ + xr.x)))); \
        float z1_ = fmaf(A0_, w0.y, fmaf(A1_, w1.y, fmaf(A2_, w2.y, fmaf(A3_, w3.y, xl1_ + xr.y)))); \
        float z2_ = fmaf(A0_, w0.z, fmaf(A1_, w1.z, fmaf(A2_, w2.z, fmaf(A3_, w3.z, xl2_ + xr.z)))); \
        float z3_ = fmaf(A0_, w0.w, fmaf(A1_, w1.w, fmaf(A2_, w2.w, fmaf(A3_, w3.w, xl3_ + xr.w)))); \
        z0_ = fmaxf(z0_, 0.2f * z0_);                                            \
        z1_ = fmaxf(z1_, 0.2f * z1_);                                            \
        z2_ = fmaxf(z2_, 0.2f * z2_);                                            \
        z3_ = fmaxf(z3_, 0.2f * z3_);                                            \
        float v_ = fmaf(z3_, at.w, fmaf(z2_, at.z, fmaf(z1_, at.y, z0_ * at.x))); \
        v_ += __shfl_xor(v_, 1);                                                 \
        v_ += __shfl_xor(v_, 2);                                                 \
        v_ += __shfl_xor(v_, 4);                                                 \
        v_ += __shfl_xor(v_, 8);                                                 \
        float p_ = valid_ ? __expf(v_) : 0.f;                                    \
        l += p_;                                                                 \
        acc.x = fmaf(p_, xl0_, acc.x);                                           \
        acc.y = fmaf(p_, xl1_, acc.y);                                           \
        acc.z = fmaf(p_, xl2_, acc.z);                                           \
        acc.w = fmaf(p_, xl3_, acc.w);                                           \
    }

    int it = 0;
    for (; it + 2 <= niter; it += 2) {
        int eb = i0 + g + it * 4;
        GAT_EDGE_BODY(eb)
        GAT_EDGE_BODY(eb + 4)
    }
    if (it < niter) {
        GAT_EDGE_BODY(i0 + g + it * 4)
    }
#undef GAT_EDGE_BODY

    // combine the 4 edge-groups (once per dst)
    l += __shfl_xor(l, 16);      l += __shfl_xor(l, 32);
    acc.x += __shfl_xor(acc.x, 16); acc.x += __shfl_xor(acc.x, 32);
    acc.y += __shfl_xor(acc.y, 16); acc.y += __shfl_xor(acc.y, 32);
    acc.z += __shfl_xor(acc.z, 16); acc.z += __shfl_xor(acc.z, 32);
    acc.w += __shfl_xor(acc.w, 16); acc.w += __shfl_xor(acc.w, 32);

    if (g == 0) {
        float inv = 1.f / (l + 1e-16f);
        const float4 b4 = *(const float4*)&bias[c0];
        float o0 = fmaf(acc.x, inv, b4.x);
        float o1 = fmaf(acc.y, inv, b4.y);
        float o2 = fmaf(acc.z, inv, b4.z);
        float o3 = fmaf(acc.w, inv, b4.w);
        if (ELU) {
            o0 = o0 > 0.f ? o0 : expf(o0) - 1.f;
            o1 = o1 > 0.f ? o1 : expf(o1) - 1.f;
            o2 = o2 > 0.f ? o2 : expf(o2) - 1.f;
            o3 = o3 > 0.f ? o3 : expf(o3) - 1.f;
        }
        if (POOLF) {
            int b = idx_at(batch, dst, flags[2]);
            atomicAdd(&pool[b * 64 + c0 + 0], o0);
            atomicAdd(&pool[b * 64 + c0 + 1], o1);
            atomicAdd(&pool[b * 64 + c0 + 2], o2);
            atomicAdd(&pool[b * 64 + c0 + 3], o3);
            if (lane == 0) atomicAdd(&cnt[b], 1.f);
        } else {
            *(float4*)&out[dst * Dout + c0] = make_float4(o0, o1, o2, o3);
        }
    }
}

// ---------------------------------------------------------------------------
// MLP head: one block (64 threads) per graph; fp32 output
// ---------------------------------------------------------------------------
__global__ void mlp_head(const float* __restrict__ pool, const float* __restrict__ cnt,
                         const float* __restrict__ mW1, const float* __restrict__ mb1,
                         const float* __restrict__ mW2, const float* __restrict__ mb2,
                         const float* __restrict__ mW3, const float* __restrict__ mb3,
                         float* __restrict__ out) {
    __shared__ float g[64], s1[32], s2[16];
    int b = blockIdx.x, t = threadIdx.x;
    float c = fmaxf(cnt[b], 1.f);
    g[t] = pool[b * 64 + t] / c;
    __syncthreads();
    if (t < 32) {
        float a = 0.f;
        for (int k = 0; k < 64; k++) a = fmaf(g[k], mW1[k * 32 + t], a);
        s1[t] = fmaxf(a + mb1[t], 0.f);
    }
    __syncthreads();
    if (t < 16) {
        float a = 0.f;
        for (int k = 0; k < 32; k++) a = fmaf(s1[k], mW2[k * 16 + t], a);
        s2[t] = fmaxf(a + mb2[t], 0.f);
    }
    __syncthreads();
    if (t < 4) {
        float a = 0.f;
        for (int k = 0; k < 16; k++) a = fmaf(s2[k], mW3[k * 4 + t], a);
        out[b * 4 + t] = a + mb3[t];
    }
}

// ---------------------------------------------------------------------------

extern "C" void kernel_launch(void* const* d_in, const int* in_sizes, int n_in,
                              void* d_out, int out_size, void* d_ws, size_t ws_size,
                              hipStream_t stream) {
    const void* ei    = d_in[1];
    const void* batch = d_in[3];

    // ---- canonicalization table: the 29 float inputs in dict order ----
    int fidx[29];
    fidx[0] = 0;  // x
    fidx[1] = 2;  // edge_attr
    for (int i = 0; i < 21; i++) fidx[2 + i] = 4 + i;
    for (int i = 0; i < 6; i++) fidx[23 + i] = 25 + i;

    Segs S;
    int off = 0;
    for (int i = 0; i < 29; i++) {
        S.src[i] = d_in[fidx[i]];
        S.off[i] = off;
        off += in_sizes[fidx[i]];
    }
    S.off[29] = off;
    const int total = off;

    // ---- workspace layout (16B-aligned sections) ----
    char* p = (char*)d_ws;
    int*   FLAGS  = (int*)p;                 p += 16;
    float* CONV   = (float*)p;               p += sizeof(float) * total;  p = align16(p);
    int*   DEG    = (int*)p;                 p += sizeof(int) * NNODES;
    int*   ROWPTR = (int*)p;                 p += sizeof(int) * (NNODES + 1);
    int*   CURSOR = (int*)p;                 p += sizeof(int) * (NNODES + 1);  p = align16(p);
    int2*  CSR    = (int2*)p;                p += sizeof(int2) * NEDGES;  p = align16(p);
    u16*   EAH    = (u16*)p;                 p += sizeof(u16) * NEDGES * 4;  p = align16(p);
    u16*   WT2L   = (u16*)p;                 p += sizeof(u16) * 256 * 256;
    u16*   WT2R   = (u16*)p;                 p += sizeof(u16) * 256 * 256;
    u16*   WT3L   = (u16*)p;                 p += sizeof(u16) * 64 * 256;
    u16*   WT3R   = (u16*)p;                 p += sizeof(u16) * 64 * 256;  p = align16(p);
    u16*   XLb    = (u16*)p;                 p += sizeof(u16) * NNODES * 256;  p = align16(p);
    float* XRb    = (float*)p;               p += sizeof(float) * NNODES * 256;
    float* ACC    = (float*)p;               p += sizeof(float) * NNODES * 256;
    float* POOL   = (float*)p;               p += sizeof(float) * NGRAPH * 64;
    float* CNT    = (float*)p;               p += sizeof(float) * NGRAPH;

    const float* CX  = CONV + S.off[0];
    const float* CP[21];
    for (int i = 0; i < 21; i++) CP[i] = CONV + S.off[2 + i];
    const float* CmW1 = CONV + S.off[23];
    const float* Cmb1 = CONV + S.off[24];
    const float* CmW2 = CONV + S.off[25];
    const float* Cmb2 = CONV + S.off[26];
    const float* CmW3 = CONV + S.off[27];
    const float* Cmb3 = CONV + S.off[28];

    // ---- sniff + fused preprocessing (convert/ea/W-pack/zero-init) ----
    sniff_all<<<1, 256, 0, stream>>>(d_in[0], ei, batch, FLAGS);
    int pre_total = total + NEDGES * 4 + 65536 * 2 + 16384 * 2 + NNODES + NGRAPH * 65;
    preprocess<<<(pre_total + 255) / 256, 256, 0, stream>>>(
        S, FLAGS, CONV, total, EAH, WT2L, WT2R, WT3L, WT3R, DEG, POOL);

    // ---- CSR build (graph identical across layers: build once) ----
    csr_hist<<<(NEDGES + 255) / 256, 256, 0, stream>>>(ei, FLAGS, DEG);
    csr_scan<<<1, 1024, 0, stream>>>(DEG, ROWPTR, CURSOR);
    csr_scatter<<<(NEDGES + 255) / 256, 256, 0, stream>>>(ei, FLAGS, CURSOR, CSR);

    // ---- layer 1: x (N x 12) -> ACC (N x 256), ELU ----
    lin_gemm<4, 12, 256, false><<<NNODES / 16, 256, 0, stream>>>(CX, CP[0], CP[1], CP[2], CP[3], XLb, XRb);
    gat_agg<4, true, false><<<NNODES, 256, 0, stream>>>(ROWPTR, CSR, XLb, XRb, EAH,
        CP[4], CP[5], CP[6], ACC, batch, FLAGS, POOL, CNT);

    // ---- layer 2: ACC (N x 256) -> ACC, ELU (MFMA GEMM) ----
    lin_gemm_mfma<256><<<NNODES / 16, 256, 0, stream>>>(ACC, WT2L, CP[8], WT2R, CP[10], XLb, XRb);
    gat_agg<4, true, false><<<NNODES, 256, 0, stream>>>(ROWPTR, CSR, XLb, XRb, EAH,
        CP[11], CP[12], CP[13], ACC, batch, FLAGS, POOL, CNT);

    // ---- layer 3: ACC (N x 256) -> pooled directly (MFMA GEMM + fused pool) ----
    lin_gemm_mfma<64><<<NNODES / 16, 256, 0, stream>>>(ACC, WT3L, CP[15], WT3R, CP[17], XLb, XRb);
    gat_agg<1, false, true><<<NNODES, 64, 0, stream>>>(ROWPTR, CSR, XLb, XRb, EAH,
        CP[18], CP[19], CP[20], ACC, batch, FLAGS, POOL, CNT);

    // ---- MLP head ----
    mlp_head<<<NGRAPH, 64, 0, stream>>>(POOL, CNT, CmW1, Cmb1, CmW2, Cmb2, CmW3, Cmb3, (float*)d_out);
}